// Round 10
// baseline (1008.483 us; speedup 1.0000x reference)
//
#include <hip/hip_runtime.h>
#include <hip/hip_bf16.h>
#include <hip/hip_fp16.h>
#include <stdint.h>

// Problem: B=4, C=64, H=W=64, L=4096.
// Outputs: y [4,64,64,64] (1048576 f32) then w [4,4096*64,3,3] (9437184 f32).
//
// Algebra: scores[(p,q),(y,x)] = sum_{a,b in -1..1} R[(p+a,q+b),(y+a,x+b)]
//          R[uv,st] = sum_c f[c,uv]*b[c,st]        (K=64 channel GEMM, exact fp32)
//          y[c,pq]  = sum_l P[pq,l]*b[c,l]         (bf16 MFMA, barrier-free direct loads)
//          P[pq,l]  = (1/9) sum_{a,b} attn[(pq+(a,b)), l+a*64+b]
//
// attn stored UNNORMALIZED per 256-key chunk: exp(s - mref_c) + per-(row,chunk)
// fp16 scale table; k_pstencil5 applies scale per TAP-KEY'S chunk at staging.
// Round-10 FIX: scale epilogue needs TWO uint4 stores (16 halves = 32 B);
// round 9's single 16-B store left chunks 8..15 poisoned -> absmax 2.24.
//
// Workspace tiers (nb): G4 / G2 / G1 = 96.125 MiB per batch.
// Per-batch strides: R 16777216 f32 | attn 16777216 bf16 | scale 65536 fp16;
// P overlays R (stride 33554432 bf16 within R's 64MiB slot).

typedef unsigned short ushort_t;
typedef __attribute__((ext_vector_type(8))) short bf16x8;
typedef __attribute__((ext_vector_type(4))) float f32x4;

#define RSTRIDE  16777216ull   // floats per batch (R)
#define ASTRIDE  16777216ull   // ushorts per batch (attn)
#define PSTRIDE  33554432ull   // ushorts per batch slot for P (overlays R)
#define SSTRIDE  65536ull      // halves per batch (scale: 4096 rows x 16 chunks)

__device__ __forceinline__ float bf2f(ushort_t u){
  union { float f; uint32_t i; } v; v.i = ((uint32_t)u) << 16; return v.f;
}
__device__ __forceinline__ ushort_t f2bf(float f){
  union { float f; uint32_t i; } v; v.f = f;
  uint32_t x = v.i;
  return (ushort_t)((x + 0x7fffu + ((x >> 16) & 1u)) >> 16);  // RNE
}

// ---- k_prep2: w output via LDS slab + coalesced float4 dump; zero y ----
__global__ __launch_bounds__(256) void k_prep2(const float* __restrict__ bin,
                                               float* __restrict__ wout,
                                               float* __restrict__ yzero){
  __shared__ float ls[2304];                     // 256 threads x 9 floats
  int tid = threadIdx.x;
  int t = blockIdx.x * 256 + tid;                // (bb, l, c), c fastest
  yzero[t] = 0.f;
  int c  = t & 63;
  int l  = (t >> 6) & 4095;
  int bb = t >> 18;
  int y = l >> 6, x = l & 63;
  const float* src = bin + (((size_t)(bb * 64 + c)) << 12);
  float* dst = ls + tid * 9;
  #pragma unroll
  for (int i = 0; i < 3; i++){
    int yy = y + i - 1;
    #pragma unroll
    for (int j = 0; j < 3; j++){
      int xx = x + j - 1;
      float v = 0.f;
      if ((unsigned)yy < 64u && (unsigned)xx < 64u) v = src[(yy << 6) + xx];
      dst[i * 3 + j] = v;
    }
  }
  __syncthreads();
  float* wbase = wout + (size_t)blockIdx.x * 2304;
  #pragma unroll
  for (int idx = tid; idx < 576; idx += 256)
    *(float4*)(wbase + (idx << 2)) = *(const float4*)(ls + (idx << 2));
}

// ---- k_rgemm: R[m,n] = sum_c f[c,m] * b[c,n]  (fp32 exact), 128x128 tile ----
__global__ __launch_bounds__(256, 2) void k_rgemm(const float* __restrict__ f,
                                                  const float* __restrict__ bin,
                                                  float* __restrict__ R,
                                                  int bt0){
  __shared__ float As[64][128];
  __shared__ float Bs[64][128];
  int bt = bt0 + blockIdx.z;
  int m0 = blockIdx.x << 7;
  int n0 = blockIdx.y << 7;
  const float* fb = f   + (((size_t)bt) << 18);
  const float* bb = bin + (((size_t)bt) << 18);
  float* Rb = R + (size_t)blockIdx.z * RSTRIDE;
  int t = threadIdx.x;
  for (int idx = t; idx < 64 * 128; idx += 256){
    int c = idx >> 7, m = idx & 127;
    As[c][m] = fb[(c << 12) + m0 + m];
    Bs[c][m] = bb[(c << 12) + n0 + m];
  }
  __syncthreads();
  int tx = t & 15, ty = t >> 4;
  float acc[8][8];
  #pragma unroll
  for (int i = 0; i < 8; i++)
    #pragma unroll
    for (int j = 0; j < 8; j++) acc[i][j] = 0.f;

  for (int c = 0; c < 64; c++){
    float4 a0 = *(const float4*)&As[c][(ty << 3)];
    float4 a1 = *(const float4*)&As[c][(ty << 3) + 4];
    float4 b0 = *(const float4*)&Bs[c][(tx << 2)];
    float4 b1 = *(const float4*)&Bs[c][64 + (tx << 2)];
    float av[8] = {a0.x, a0.y, a0.z, a0.w, a1.x, a1.y, a1.z, a1.w};
    float bv[8] = {b0.x, b0.y, b0.z, b0.w, b1.x, b1.y, b1.z, b1.w};
    #pragma unroll
    for (int i = 0; i < 8; i++)
      #pragma unroll
      for (int j = 0; j < 8; j++) acc[i][j] += av[i] * bv[j];
  }
  #pragma unroll
  for (int i = 0; i < 8; i++){
    float* dst = Rb + ((size_t)(m0 + (ty << 3) + i) << 12) + n0;
    *(float4*)(dst + (tx << 2))      = make_float4(acc[i][0], acc[i][1], acc[i][2], acc[i][3]);
    *(float4*)(dst + 64 + (tx << 2)) = make_float4(acc[i][4], acc[i][5], acc[i][6], acc[i][7]);
  }
}

// =====================================================================
// k_softmax4: fused single-pass stencil + online softmax, 256-key chunks.
// WG = 4x2 query tile. Per chunk: stage 24 R rows (+-68 halo) into 37.6KB
// LDS (4 WG/CU), 9-tap stencil with shfl edges, lane-uniform chunk max,
// immediate unnormalized bf16 attn store. Epilogue: fp16 scale table.
// blockIdx.y = batch.
// =====================================================================
__global__ __launch_bounds__(256, 4) void k_softmax4(const float* __restrict__ Rg,
                                                     ushort_t* __restrict__ attng,
                                                     __half* __restrict__ scaleg){
  __shared__ float Rt[24][392];                 // 37632 B
  const int t  = threadIdx.x;
  const int bb = blockIdx.x;
  const float* R = Rg + (size_t)blockIdx.y * RSTRIDE;
  ushort_t* attn = attng + (size_t)blockIdx.y * ASTRIDE;
  __half* scale = scaleg + (size_t)blockIdx.y * SSTRIDE;
  const int inner = bb >> 3;
  const int ty = ((bb & 7) << 1) | (inner & 1); // XCD band swizzle
  const int tx = inner >> 1;
  const int p0 = ty << 2, q0 = tx << 1;
  const int qi = t >> 5, kt = t & 31;
  const int pi = qi >> 1, qj = qi & 1;
  const int ktx = kt & 15;

  float M = -3.0e38f, L = 0.f;
  float mref[16];
  float4 rbuf[10];                              // 2352 float4s staged / 256 threads

  int row = ((p0 + pi) << 6) + q0 + qj;
  ushort_t* arow = attn + ((size_t)row << 12);

  // prefetch chunk 0
  #pragma unroll
  for (int i = 0; i < 10; i++){
    int idx = t + (i << 8);
    float4 v = make_float4(0.f, 0.f, 0.f, 0.f);
    if (idx < 2352){
      unsigned r = (unsigned)idx / 98u;
      int fo = idx - (int)r * 98;
      int rp = p0 - 1 + (int)(r >> 2);
      int rq = q0 - 1 + (int)(r & 3);
      int kg = -68 + (fo << 2);
      if ((unsigned)rp < 64u && (unsigned)rq < 64u && (unsigned)kg <= 4092u)
        v = *(const float4*)(R + (((size_t)((rp << 6) + rq)) << 12) + kg);
    }
    rbuf[i] = v;
  }

  #pragma unroll
  for (int c = 0; c < 16; c++){
    __syncthreads();
    #pragma unroll
    for (int i = 0; i < 10; i++){
      int idx = t + (i << 8);
      if (idx < 2352) ((float4*)&Rt[0][0])[idx] = rbuf[i];
    }
    __syncthreads();
    if (c < 15){
      const int k0 = (c + 1) << 8;
      #pragma unroll
      for (int i = 0; i < 10; i++){
        int idx = t + (i << 8);
        float4 v = make_float4(0.f, 0.f, 0.f, 0.f);
        if (idx < 2352){
          unsigned r = (unsigned)idx / 98u;
          int fo = idx - (int)r * 98;
          int rp = p0 - 1 + (int)(r >> 2);
          int rq = q0 - 1 + (int)(r & 3);
          int kg = k0 - 68 + (fo << 2);
          if ((unsigned)rp < 64u && (unsigned)rq < 64u && (unsigned)kg <= 4092u)
            v = *(const float4*)(R + (((size_t)((rp << 6) + rq)) << 12) + kg);
        }
        rbuf[i] = v;
      }
    }
    // 9-tap stencil from LDS; +-1 key edges via cross-lane shfl
    float4 sv[2];
    #pragma unroll
    for (int j = 0; j < 2; j++){
      int y = (c << 2) + (j << 1) + (kt >> 4);
      int sa0 = (j << 7) + (kt << 2) + 68;
      float4 s = make_float4(0.f, 0.f, 0.f, 0.f);
      #pragma unroll
      for (int a = -1; a <= 1; a++){
        if ((unsigned)(y + a) < 64u){
          int rb = (pi + 1 + a) << 2;
          int sa = sa0 + (a << 6);
          float4 A0 = *(const float4*)&Rt[rb + qj][sa];
          float4 A1 = *(const float4*)&Rt[rb + qj + 1][sa];
          float4 A2 = *(const float4*)&Rt[rb + qj + 2][sa];
          float Lv = __shfl_up(A0.w, 1);
          float Rv = __shfl_down(A2.x, 1);
          s.x += (ktx == 0 ? 0.f : Lv) + A1.x + A2.y;
          s.y += A0.x + A1.y + A2.z;
          s.z += A0.y + A1.z + A2.w;
          s.w += A0.z + A1.w + (ktx == 15 ? 0.f : Rv);
        }
      }
      s.x *= 10.f; s.y *= 10.f; s.z *= 10.f; s.w *= 10.f;
      sv[j] = s;
    }
    // lane-uniform chunk max over this query's 32 lanes
    float mc = M;
    #pragma unroll
    for (int j = 0; j < 2; j++)
      mc = fmaxf(mc, fmaxf(fmaxf(sv[j].x, sv[j].y), fmaxf(sv[j].z, sv[j].w)));
    #pragma unroll
    for (int off = 1; off < 32; off <<= 1) mc = fmaxf(mc, __shfl_xor(mc, off));
    // online update + immediate unnormalized bf16 store
    float lnew = L * __expf(M - mc);
    #pragma unroll
    for (int j = 0; j < 2; j++){
      float ex = __expf(sv[j].x - mc), ey = __expf(sv[j].y - mc);
      float ez = __expf(sv[j].z - mc), ew = __expf(sv[j].w - mc);
      lnew += ex + ey + ez + ew;
      ushort4 o; o.x = f2bf(ex); o.y = f2bf(ey); o.z = f2bf(ez); o.w = f2bf(ew);
      *(ushort4*)&arow[(c << 8) + (j << 7) + (kt << 2)] = o;
    }
    L = lnew; M = mc; mref[c] = mc;
  }
  // L per-lane partial; M/mref lane-uniform -> plain cross-lane sum
  #pragma unroll
  for (int off = 1; off < 32; off <<= 1) L += __shfl_xor(L, off);
  if (kt == 0){
    float invL = 1.0f / L;
    __half hs[16];
    #pragma unroll
    for (int c = 0; c < 16; c++) hs[c] = __float2half(__expf(mref[c] - M) * invL);
    // 16 halves = 32 B -> TWO uint4 stores (round-9 bug: single store)
    *(uint4*)&scale[(row << 4)]     = ((uint4*)hs)[0];
    *(uint4*)&scale[(row << 4) + 8] = ((uint4*)hs)[1];
  }
}

// =====================================================================
// k_pstencil5: P = (1/9)*stencil9(attn_unnorm * scale), scale per tap-key
// chunk (key>>8) applied at staging. 256-key chunks, 38.2KB LDS -> 4 WG/CU.
// blockIdx.y = batch.
// =====================================================================
__global__ __launch_bounds__(256, 4) void k_pstencil5(const ushort_t* __restrict__ attng,
                                                      const __half* __restrict__ scaleg,
                                                      ushort_t* __restrict__ Pg){
  __shared__ float At[24][392];                 // 37632 B
  __shared__ float Sc[24][16];                  // 1536 B
  const int t  = threadIdx.x;
  const int bb = blockIdx.x;
  const ushort_t* attn = attng + (size_t)blockIdx.y * ASTRIDE;
  const __half* scale = scaleg + (size_t)blockIdx.y * SSTRIDE;
  ushort_t* P = Pg + (size_t)blockIdx.y * PSTRIDE;
  const int inner = bb >> 3;
  const int ty = ((bb & 7) << 1) | (inner & 1);
  const int tx = inner >> 1;
  const int p0 = ty << 2, q0 = tx << 1;
  const int qi = t >> 5, kt = t & 31;
  const int pi = qi >> 1, qj = qi & 1;
  const int ktx = kt & 15;

  int row = ((p0 + pi) << 6) + q0 + qj;
  ushort_t* prow = P + ((size_t)row << 12);
  const float inv9 = 1.0f / 9.0f;

  for (int i = t; i < 384; i += 256){
    int r = i >> 4, cc = i & 15;
    int rp = p0 - 1 + (r >> 2);
    int rq = q0 - 1 + (r & 3);
    float v = 0.f;
    if ((unsigned)rp < 64u && (unsigned)rq < 64u)
      v = __half2float(scale[(((rp << 6) + rq) << 4) + cc]);
    Sc[r][cc] = v;
  }

  uint2 rbuf[10];
  #pragma unroll
  for (int i = 0; i < 10; i++){
    int idx = t + (i << 8);
    uint2 v = make_uint2(0u, 0u);
    if (idx < 2352){
      unsigned r = (unsigned)idx / 98u;
      int fo = idx - (int)r * 98;
      int rp = p0 - 1 + (int)(r >> 2);
      int rq = q0 - 1 + (int)(r & 3);
      int kg = -68 + (fo << 2);
      if ((unsigned)rp < 64u && (unsigned)rq < 64u && (unsigned)kg <= 4092u)
        v = *(const uint2*)(attn + (((size_t)((rp << 6) + rq)) << 12) + kg);
    }
    rbuf[i] = v;
  }

  #pragma unroll
  for (int c = 0; c < 16; c++){
    __syncthreads();   // first iter also fences the Sc stores
    #pragma unroll
    for (int i = 0; i < 10; i++){
      int idx = t + (i << 8);
      if (idx < 2352){
        unsigned r = (unsigned)idx / 98u;
        int fo = idx - (int)r * 98;
        int key = (c << 8) - 68 + (fo << 2);
        key = key < 0 ? 0 : (key > 4095 ? 4095 : key);
        float sc = Sc[r][key >> 8];
        uint2 u = rbuf[i];
        float4 w;
        { union { uint32_t q; float f; } a_, b_;
          a_.q = u.x << 16; b_.q = u.x & 0xffff0000u; w.x = a_.f * sc; w.y = b_.f * sc; }
        { union { uint32_t q; float f; } a_, b_;
          a_.q = u.y << 16; b_.q = u.y & 0xffff0000u; w.z = a_.f * sc; w.w = b_.f * sc; }
        ((float4*)&At[0][0])[idx] = w;
      }
    }
    __syncthreads();
    if (c < 15){
      const int k0 = (c + 1) << 8;
      #pragma unroll
      for (int i = 0; i < 10; i++){
        int idx = t + (i << 8);
        uint2 v = make_uint2(0u, 0u);
        if (idx < 2352){
          unsigned r = (unsigned)idx / 98u;
          int fo = idx - (int)r * 98;
          int rp = p0 - 1 + (int)(r >> 2);
          int rq = q0 - 1 + (int)(r & 3);
          int kg = k0 - 68 + (fo << 2);
          if ((unsigned)rp < 64u && (unsigned)rq < 64u && (unsigned)kg <= 4092u)
            v = *(const uint2*)(attn + (((size_t)((rp << 6) + rq)) << 12) + kg);
        }
        rbuf[i] = v;
      }
    }
    #pragma unroll
    for (int j = 0; j < 2; j++){
      int y = (c << 2) + (j << 1) + (kt >> 4);
      int sa0 = (j << 7) + (kt << 2) + 68;
      float4 s = make_float4(0.f, 0.f, 0.f, 0.f);
      #pragma unroll
      for (int a = -1; a <= 1; a++){
        if ((unsigned)(y + a) < 64u){
          int rb = (pi + 1 + a) << 2;
          int sa = sa0 + (a << 6);
          float4 A0 = *(const float4*)&At[rb + qj][sa];
          float4 A1 = *(const float4*)&At[rb + qj + 1][sa];
          float4 A2 = *(const float4*)&At[rb + qj + 2][sa];
          float Lv = __shfl_up(A0.w, 1);
          float Rv = __shfl_down(A2.x, 1);
          s.x += (ktx == 0 ? 0.f : Lv) + A1.x + A2.y;
          s.y += A0.x + A1.y + A2.z;
          s.z += A0.y + A1.z + A2.w;
          s.w += A0.z + A1.w + (ktx == 15 ? 0.f : Rv);
        }
      }
      ushort4 o;
      o.x = f2bf(s.x * inv9);
      o.y = f2bf(s.y * inv9);
      o.z = f2bf(s.z * inv9);
      o.w = f2bf(s.w * inv9);
      *(ushort4*)&prow[(c << 8) + (j << 7) + (kt << 2)] = o;
    }
  }
}

// =====================================================================
// k_ygemm2: y[c,pq] = sum_l P[pq,l]*b[c,l] -- barrier-free, LDS-free,
// MFMA fragments loaded directly from global. blockIdx.z = batch.
// =====================================================================
__global__ __launch_bounds__(256) void k_ygemm2(const float* __restrict__ bin,
                                                const ushort_t* __restrict__ Pg,
                                                float* __restrict__ y,
                                                int bt0){
  const int t = threadIdx.x;
  const int lane = t & 63, wv = t >> 6;
  const int n = lane & 15, quad = lane >> 4;
  const int bt = bt0 + blockIdx.z;
  const int pq0 = blockIdx.x << 6;
  const int k0  = blockIdx.y << 8;          // 256 K per block
  const float*    bbase = bin + (((size_t)bt) << 18);
  const ushort_t* Prow  = Pg + (size_t)blockIdx.z * PSTRIDE
                             + (((size_t)(pq0 + (wv << 4) + n)) << 12);

  f32x4 acc[4];
  #pragma unroll
  for (int cb = 0; cb < 4; cb++) acc[cb] = (f32x4){0.f, 0.f, 0.f, 0.f};

  #pragma unroll 2
  for (int kb = k0; kb < k0 + 256; kb += 32){
    int ko = kb + (quad << 3);
    bf16x8 pf = *(const bf16x8*)(Prow + ko);
    #pragma unroll
    for (int cb = 0; cb < 4; cb++){
      const float* bp = bbase + (((cb << 4) + n) << 12) + ko;
      float4 b0 = *(const float4*)bp;
      float4 b1 = *(const float4*)(bp + 4);
      bf16x8 bf;
      bf[0] = (short)f2bf(b0.x); bf[1] = (short)f2bf(b0.y);
      bf[2] = (short)f2bf(b0.z); bf[3] = (short)f2bf(b0.w);
      bf[4] = (short)f2bf(b1.x); bf[5] = (short)f2bf(b1.y);
      bf[6] = (short)f2bf(b1.z); bf[7] = (short)f2bf(b1.w);
      acc[cb] = __builtin_amdgcn_mfma_f32_16x16x32_bf16(bf, pf, acc[cb], 0, 0, 0);
    }
  }
  int pql = pq0 + (wv << 4) + n;
  #pragma unroll
  for (int cb = 0; cb < 4; cb++)
    #pragma unroll
    for (int r = 0; r < 4; r++){
      int c = (cb << 4) + (quad << 2) + r;
      atomicAdd(&y[(((size_t)(bt * 64 + c)) << 12) + pql], acc[cb][r]);
    }
}

extern "C" void kernel_launch(void* const* d_in, const int* in_sizes, int n_in,
                              void* d_out, int out_size, void* d_ws, size_t ws_size,
                              hipStream_t stream){
  const float* f = (const float*)d_in[0];
  const float* b = (const float*)d_in[1];
  float* out  = (float*)d_out;
  float* yout = out;
  float* wout = out + 1048576;

  const size_t RB  = RSTRIDE * 4;   // 64 MiB fp32 R per batch
  const size_t AB  = ASTRIDE * 2;   // 32 MiB bf16 attn per batch
  const size_t SCB = SSTRIDE * 2;   // 128 KiB fp16 scale per batch
  const size_t PER = RB + AB + SCB;

  int nb = 1;
  if (ws_size >= 4 * PER) nb = 4;
  else if (ws_size >= 2 * PER) nb = 2;

  k_prep2<<<4096, 256, 0, stream>>>(b, wout, yout);   // also zeroes y

  // Layout per group: R[nb] @0 | attn[nb] @nb*RB | scale[nb] @nb*(RB+AB); P overlays R.
  float*    R     = (float*)d_ws;
  ushort_t* attn  = (ushort_t*)((char*)d_ws + (size_t)nb * RB);
  __half*   scale = (__half*)((char*)d_ws + (size_t)nb * (RB + AB));
  ushort_t* P     = (ushort_t*)d_ws;
  for (int bt0 = 0; bt0 < 4; bt0 += nb){
    k_rgemm    <<<dim3(32, 32, nb), 256, 0, stream>>>(f, b, R, bt0);
    k_softmax4 <<<dim3(512, nb),    256, 0, stream>>>(R, attn, scale);
    k_pstencil5<<<dim3(512, nb),    256, 0, stream>>>(attn, scale, P);
    k_ygemm2   <<<dim3(64, 16, nb), 256, 0, stream>>>(b, P, yout, bt0);
  }
}

// Round 11
// 584.664 us; speedup vs baseline: 1.7249x; 1.7249x over previous
//
#include <hip/hip_runtime.h>
#include <hip/hip_bf16.h>
#include <hip/hip_fp16.h>
#include <stdint.h>

// Problem: B=4, C=64, H=W=64, L=4096.
// Outputs: y [4,64,64,64] (1048576 f32) then w [4,4096*64,3,3] (9437184 f32).
//
// Algebra: scores[(p,q),(y,x)] = sum_{a,b in -1..1} R[(p+a,q+b),(y+a,x+b)]
//          R[uv,st] = sum_c f[c,uv]*b[c,st]        (K=64 channel GEMM, exact fp32)
//          y[c,pq]  = sum_l P[pq,l]*b[c,l]         (bf16 MFMA, barrier-free direct loads)
//          P[pq,l]  = (1/9) sum_{a,b} attn[(pq+(a,b)), l+a*64+b]
//
// attn stored UNNORMALIZED per 256-key chunk: exp(s - mref_c) + per-(row,chunk)
// fp16 scale table; k_pstencil5 applies scale per TAP-KEY'S chunk at staging.
//
// ROUND-11: launch_bounds (256,4)->(256,2) on the stencil kernels. Round 10's
// min-waves=4 forced a 64-VGPR cap -> rbuf spilled to scratch (FETCH/WRITE
// doubled, 211us). With (256,2) the ~100-VGPR live set lands in the <=128
// bucket -> HW gives 4 waves/EU anyway (LDS 37.9KB allows exactly 4 WG/CU).
//
// Workspace tiers (nb): G4 / G2 / G1 = 96.125 MiB per batch.
// Per-batch strides: R 16777216 f32 | attn 16777216 bf16 | scale 65536 fp16;
// P overlays R (stride 33554432 bf16 within R's 64MiB slot).

typedef unsigned short ushort_t;
typedef __attribute__((ext_vector_type(8))) short bf16x8;
typedef __attribute__((ext_vector_type(4))) float f32x4;

#define RSTRIDE  16777216ull   // floats per batch (R)
#define ASTRIDE  16777216ull   // ushorts per batch (attn)
#define PSTRIDE  33554432ull   // ushorts per batch slot for P (overlays R)
#define SSTRIDE  65536ull      // halves per batch (scale: 4096 rows x 16 chunks)

__device__ __forceinline__ float bf2f(ushort_t u){
  union { float f; uint32_t i; } v; v.i = ((uint32_t)u) << 16; return v.f;
}
__device__ __forceinline__ ushort_t f2bf(float f){
  union { float f; uint32_t i; } v; v.f = f;
  uint32_t x = v.i;
  return (ushort_t)((x + 0x7fffu + ((x >> 16) & 1u)) >> 16);  // RNE
}

// ---- k_prep2: w output via LDS slab + coalesced float4 dump; zero y ----
__global__ __launch_bounds__(256) void k_prep2(const float* __restrict__ bin,
                                               float* __restrict__ wout,
                                               float* __restrict__ yzero){
  __shared__ float ls[2304];                     // 256 threads x 9 floats
  int tid = threadIdx.x;
  int t = blockIdx.x * 256 + tid;                // (bb, l, c), c fastest
  yzero[t] = 0.f;
  int c  = t & 63;
  int l  = (t >> 6) & 4095;
  int bb = t >> 18;
  int y = l >> 6, x = l & 63;
  const float* src = bin + (((size_t)(bb * 64 + c)) << 12);
  float* dst = ls + tid * 9;
  #pragma unroll
  for (int i = 0; i < 3; i++){
    int yy = y + i - 1;
    #pragma unroll
    for (int j = 0; j < 3; j++){
      int xx = x + j - 1;
      float v = 0.f;
      if ((unsigned)yy < 64u && (unsigned)xx < 64u) v = src[(yy << 6) + xx];
      dst[i * 3 + j] = v;
    }
  }
  __syncthreads();
  float* wbase = wout + (size_t)blockIdx.x * 2304;
  #pragma unroll
  for (int idx = tid; idx < 576; idx += 256)
    *(float4*)(wbase + (idx << 2)) = *(const float4*)(ls + (idx << 2));
}

// ---- k_rgemm: R[m,n] = sum_c f[c,m] * b[c,n]  (fp32 exact), 128x128 tile ----
__global__ __launch_bounds__(256, 2) void k_rgemm(const float* __restrict__ f,
                                                  const float* __restrict__ bin,
                                                  float* __restrict__ R,
                                                  int bt0){
  __shared__ float As[64][128];
  __shared__ float Bs[64][128];
  int bt = bt0 + blockIdx.z;
  int m0 = blockIdx.x << 7;
  int n0 = blockIdx.y << 7;
  const float* fb = f   + (((size_t)bt) << 18);
  const float* bb = bin + (((size_t)bt) << 18);
  float* Rb = R + (size_t)blockIdx.z * RSTRIDE;
  int t = threadIdx.x;
  for (int idx = t; idx < 64 * 128; idx += 256){
    int c = idx >> 7, m = idx & 127;
    As[c][m] = fb[(c << 12) + m0 + m];
    Bs[c][m] = bb[(c << 12) + n0 + m];
  }
  __syncthreads();
  int tx = t & 15, ty = t >> 4;
  float acc[8][8];
  #pragma unroll
  for (int i = 0; i < 8; i++)
    #pragma unroll
    for (int j = 0; j < 8; j++) acc[i][j] = 0.f;

  for (int c = 0; c < 64; c++){
    float4 a0 = *(const float4*)&As[c][(ty << 3)];
    float4 a1 = *(const float4*)&As[c][(ty << 3) + 4];
    float4 b0 = *(const float4*)&Bs[c][(tx << 2)];
    float4 b1 = *(const float4*)&Bs[c][64 + (tx << 2)];
    float av[8] = {a0.x, a0.y, a0.z, a0.w, a1.x, a1.y, a1.z, a1.w};
    float bv[8] = {b0.x, b0.y, b0.z, b0.w, b1.x, b1.y, b1.z, b1.w};
    #pragma unroll
    for (int i = 0; i < 8; i++)
      #pragma unroll
      for (int j = 0; j < 8; j++) acc[i][j] += av[i] * bv[j];
  }
  #pragma unroll
  for (int i = 0; i < 8; i++){
    float* dst = Rb + ((size_t)(m0 + (ty << 3) + i) << 12) + n0;
    *(float4*)(dst + (tx << 2))      = make_float4(acc[i][0], acc[i][1], acc[i][2], acc[i][3]);
    *(float4*)(dst + 64 + (tx << 2)) = make_float4(acc[i][4], acc[i][5], acc[i][6], acc[i][7]);
  }
}

// =====================================================================
// k_softmax4: fused single-pass stencil + online softmax, 256-key chunks.
// WG = 4x2 query tile. Per chunk: stage 24 R rows (+-68 halo) into 37.6KB
// LDS, 9-tap stencil with shfl edges, lane-uniform chunk max, immediate
// unnormalized bf16 attn store. Epilogue: fp16 scale table (2x uint4).
// launch_bounds(256,2): ~100 VGPR -> <=128 bucket -> 4 WG/CU via LDS.
// blockIdx.y = batch.
// =====================================================================
__global__ __launch_bounds__(256, 2) void k_softmax4(const float* __restrict__ Rg,
                                                     ushort_t* __restrict__ attng,
                                                     __half* __restrict__ scaleg){
  __shared__ float Rt[24][392];                 // 37632 B
  const int t  = threadIdx.x;
  const int bb = blockIdx.x;
  const float* R = Rg + (size_t)blockIdx.y * RSTRIDE;
  ushort_t* attn = attng + (size_t)blockIdx.y * ASTRIDE;
  __half* scale = scaleg + (size_t)blockIdx.y * SSTRIDE;
  const int inner = bb >> 3;
  const int ty = ((bb & 7) << 1) | (inner & 1); // XCD band swizzle
  const int tx = inner >> 1;
  const int p0 = ty << 2, q0 = tx << 1;
  const int qi = t >> 5, kt = t & 31;
  const int pi = qi >> 1, qj = qi & 1;
  const int ktx = kt & 15;

  float M = -3.0e38f, L = 0.f;
  float mref[16];
  float4 rbuf[10];                              // 2352 float4s staged / 256 threads

  int row = ((p0 + pi) << 6) + q0 + qj;
  ushort_t* arow = attn + ((size_t)row << 12);

  // prefetch chunk 0
  #pragma unroll
  for (int i = 0; i < 10; i++){
    int idx = t + (i << 8);
    float4 v = make_float4(0.f, 0.f, 0.f, 0.f);
    if (idx < 2352){
      unsigned r = (unsigned)idx / 98u;
      int fo = idx - (int)r * 98;
      int rp = p0 - 1 + (int)(r >> 2);
      int rq = q0 - 1 + (int)(r & 3);
      int kg = -68 + (fo << 2);
      if ((unsigned)rp < 64u && (unsigned)rq < 64u && (unsigned)kg <= 4092u)
        v = *(const float4*)(R + (((size_t)((rp << 6) + rq)) << 12) + kg);
    }
    rbuf[i] = v;
  }

  #pragma unroll
  for (int c = 0; c < 16; c++){
    __syncthreads();
    #pragma unroll
    for (int i = 0; i < 10; i++){
      int idx = t + (i << 8);
      if (idx < 2352) ((float4*)&Rt[0][0])[idx] = rbuf[i];
    }
    __syncthreads();
    if (c < 15){
      const int k0 = (c + 1) << 8;
      #pragma unroll
      for (int i = 0; i < 10; i++){
        int idx = t + (i << 8);
        float4 v = make_float4(0.f, 0.f, 0.f, 0.f);
        if (idx < 2352){
          unsigned r = (unsigned)idx / 98u;
          int fo = idx - (int)r * 98;
          int rp = p0 - 1 + (int)(r >> 2);
          int rq = q0 - 1 + (int)(r & 3);
          int kg = k0 - 68 + (fo << 2);
          if ((unsigned)rp < 64u && (unsigned)rq < 64u && (unsigned)kg <= 4092u)
            v = *(const float4*)(R + (((size_t)((rp << 6) + rq)) << 12) + kg);
        }
        rbuf[i] = v;
      }
    }
    // 9-tap stencil from LDS; +-1 key edges via cross-lane shfl
    float4 sv[2];
    #pragma unroll
    for (int j = 0; j < 2; j++){
      int y = (c << 2) + (j << 1) + (kt >> 4);
      int sa0 = (j << 7) + (kt << 2) + 68;
      float4 s = make_float4(0.f, 0.f, 0.f, 0.f);
      #pragma unroll
      for (int a = -1; a <= 1; a++){
        if ((unsigned)(y + a) < 64u){
          int rb = (pi + 1 + a) << 2;
          int sa = sa0 + (a << 6);
          float4 A0 = *(const float4*)&Rt[rb + qj][sa];
          float4 A1 = *(const float4*)&Rt[rb + qj + 1][sa];
          float4 A2 = *(const float4*)&Rt[rb + qj + 2][sa];
          float Lv = __shfl_up(A0.w, 1);
          float Rv = __shfl_down(A2.x, 1);
          s.x += (ktx == 0 ? 0.f : Lv) + A1.x + A2.y;
          s.y += A0.x + A1.y + A2.z;
          s.z += A0.y + A1.z + A2.w;
          s.w += A0.z + A1.w + (ktx == 15 ? 0.f : Rv);
        }
      }
      s.x *= 10.f; s.y *= 10.f; s.z *= 10.f; s.w *= 10.f;
      sv[j] = s;
    }
    // lane-uniform chunk max over this query's 32 lanes
    float mc = M;
    #pragma unroll
    for (int j = 0; j < 2; j++)
      mc = fmaxf(mc, fmaxf(fmaxf(sv[j].x, sv[j].y), fmaxf(sv[j].z, sv[j].w)));
    #pragma unroll
    for (int off = 1; off < 32; off <<= 1) mc = fmaxf(mc, __shfl_xor(mc, off));
    // online update + immediate unnormalized bf16 store
    float lnew = L * __expf(M - mc);
    #pragma unroll
    for (int j = 0; j < 2; j++){
      float ex = __expf(sv[j].x - mc), ey = __expf(sv[j].y - mc);
      float ez = __expf(sv[j].z - mc), ew = __expf(sv[j].w - mc);
      lnew += ex + ey + ez + ew;
      ushort4 o; o.x = f2bf(ex); o.y = f2bf(ey); o.z = f2bf(ez); o.w = f2bf(ew);
      *(ushort4*)&arow[(c << 8) + (j << 7) + (kt << 2)] = o;
    }
    L = lnew; M = mc; mref[c] = mc;
  }
  // L per-lane partial; M/mref lane-uniform -> plain cross-lane sum
  #pragma unroll
  for (int off = 1; off < 32; off <<= 1) L += __shfl_xor(L, off);
  if (kt == 0){
    float invL = 1.0f / L;
    __half hs[16];
    #pragma unroll
    for (int c = 0; c < 16; c++) hs[c] = __float2half(__expf(mref[c] - M) * invL);
    // 16 halves = 32 B -> TWO uint4 stores
    *(uint4*)&scale[(row << 4)]     = ((uint4*)hs)[0];
    *(uint4*)&scale[(row << 4) + 8] = ((uint4*)hs)[1];
  }
}

// =====================================================================
// k_pstencil5: P = (1/9)*stencil9(attn_unnorm * scale), scale per tap-key
// chunk (key>>8) applied at staging. 256-key chunks, 38.2KB LDS.
// launch_bounds(256,2); blockIdx.y = batch.
// =====================================================================
__global__ __launch_bounds__(256, 2) void k_pstencil5(const ushort_t* __restrict__ attng,
                                                      const __half* __restrict__ scaleg,
                                                      ushort_t* __restrict__ Pg){
  __shared__ float At[24][392];                 // 37632 B
  __shared__ float Sc[24][16];                  // 1536 B
  const int t  = threadIdx.x;
  const int bb = blockIdx.x;
  const ushort_t* attn = attng + (size_t)blockIdx.y * ASTRIDE;
  const __half* scale = scaleg + (size_t)blockIdx.y * SSTRIDE;
  ushort_t* P = Pg + (size_t)blockIdx.y * PSTRIDE;
  const int inner = bb >> 3;
  const int ty = ((bb & 7) << 1) | (inner & 1);
  const int tx = inner >> 1;
  const int p0 = ty << 2, q0 = tx << 1;
  const int qi = t >> 5, kt = t & 31;
  const int pi = qi >> 1, qj = qi & 1;
  const int ktx = kt & 15;

  int row = ((p0 + pi) << 6) + q0 + qj;
  ushort_t* prow = P + ((size_t)row << 12);
  const float inv9 = 1.0f / 9.0f;

  for (int i = t; i < 384; i += 256){
    int r = i >> 4, cc = i & 15;
    int rp = p0 - 1 + (r >> 2);
    int rq = q0 - 1 + (r & 3);
    float v = 0.f;
    if ((unsigned)rp < 64u && (unsigned)rq < 64u)
      v = __half2float(scale[(((rp << 6) + rq) << 4) + cc]);
    Sc[r][cc] = v;
  }

  uint2 rbuf[10];
  #pragma unroll
  for (int i = 0; i < 10; i++){
    int idx = t + (i << 8);
    uint2 v = make_uint2(0u, 0u);
    if (idx < 2352){
      unsigned r = (unsigned)idx / 98u;
      int fo = idx - (int)r * 98;
      int rp = p0 - 1 + (int)(r >> 2);
      int rq = q0 - 1 + (int)(r & 3);
      int kg = -68 + (fo << 2);
      if ((unsigned)rp < 64u && (unsigned)rq < 64u && (unsigned)kg <= 4092u)
        v = *(const uint2*)(attn + (((size_t)((rp << 6) + rq)) << 12) + kg);
    }
    rbuf[i] = v;
  }

  #pragma unroll
  for (int c = 0; c < 16; c++){
    __syncthreads();   // first iter also fences the Sc stores
    #pragma unroll
    for (int i = 0; i < 10; i++){
      int idx = t + (i << 8);
      if (idx < 2352){
        unsigned r = (unsigned)idx / 98u;
        int fo = idx - (int)r * 98;
        int key = (c << 8) - 68 + (fo << 2);
        key = key < 0 ? 0 : (key > 4095 ? 4095 : key);
        float sc = Sc[r][key >> 8];
        uint2 u = rbuf[i];
        float4 w;
        { union { uint32_t q; float f; } a_, b_;
          a_.q = u.x << 16; b_.q = u.x & 0xffff0000u; w.x = a_.f * sc; w.y = b_.f * sc; }
        { union { uint32_t q; float f; } a_, b_;
          a_.q = u.y << 16; b_.q = u.y & 0xffff0000u; w.z = a_.f * sc; w.w = b_.f * sc; }
        ((float4*)&At[0][0])[idx] = w;
      }
    }
    __syncthreads();
    if (c < 15){
      const int k0 = (c + 1) << 8;
      #pragma unroll
      for (int i = 0; i < 10; i++){
        int idx = t + (i << 8);
        uint2 v = make_uint2(0u, 0u);
        if (idx < 2352){
          unsigned r = (unsigned)idx / 98u;
          int fo = idx - (int)r * 98;
          int rp = p0 - 1 + (int)(r >> 2);
          int rq = q0 - 1 + (int)(r & 3);
          int kg = k0 - 68 + (fo << 2);
          if ((unsigned)rp < 64u && (unsigned)rq < 64u && (unsigned)kg <= 4092u)
            v = *(const uint2*)(attn + (((size_t)((rp << 6) + rq)) << 12) + kg);
        }
        rbuf[i] = v;
      }
    }
    #pragma unroll
    for (int j = 0; j < 2; j++){
      int y = (c << 2) + (j << 1) + (kt >> 4);
      int sa0 = (j << 7) + (kt << 2) + 68;
      float4 s = make_float4(0.f, 0.f, 0.f, 0.f);
      #pragma unroll
      for (int a = -1; a <= 1; a++){
        if ((unsigned)(y + a) < 64u){
          int rb = (pi + 1 + a) << 2;
          int sa = sa0 + (a << 6);
          float4 A0 = *(const float4*)&At[rb + qj][sa];
          float4 A1 = *(const float4*)&At[rb + qj + 1][sa];
          float4 A2 = *(const float4*)&At[rb + qj + 2][sa];
          float Lv = __shfl_up(A0.w, 1);
          float Rv = __shfl_down(A2.x, 1);
          s.x += (ktx == 0 ? 0.f : Lv) + A1.x + A2.y;
          s.y += A0.x + A1.y + A2.z;
          s.z += A0.y + A1.z + A2.w;
          s.w += A0.z + A1.w + (ktx == 15 ? 0.f : Rv);
        }
      }
      ushort4 o;
      o.x = f2bf(s.x * inv9);
      o.y = f2bf(s.y * inv9);
      o.z = f2bf(s.z * inv9);
      o.w = f2bf(s.w * inv9);
      *(ushort4*)&prow[(c << 8) + (j << 7) + (kt << 2)] = o;
    }
  }
}

// =====================================================================
// k_ygemm2: y[c,pq] = sum_l P[pq,l]*b[c,l] -- barrier-free, LDS-free,
// MFMA fragments loaded directly from global. blockIdx.z = batch.
// =====================================================================
__global__ __launch_bounds__(256) void k_ygemm2(const float* __restrict__ bin,
                                                const ushort_t* __restrict__ Pg,
                                                float* __restrict__ y,
                                                int bt0){
  const int t = threadIdx.x;
  const int lane = t & 63, wv = t >> 6;
  const int n = lane & 15, quad = lane >> 4;
  const int bt = bt0 + blockIdx.z;
  const int pq0 = blockIdx.x << 6;
  const int k0  = blockIdx.y << 8;          // 256 K per block
  const float*    bbase = bin + (((size_t)bt) << 18);
  const ushort_t* Prow  = Pg + (size_t)blockIdx.z * PSTRIDE
                             + (((size_t)(pq0 + (wv << 4) + n)) << 12);

  f32x4 acc[4];
  #pragma unroll
  for (int cb = 0; cb < 4; cb++) acc[cb] = (f32x4){0.f, 0.f, 0.f, 0.f};

  #pragma unroll 2
  for (int kb = k0; kb < k0 + 256; kb += 32){
    int ko = kb + (quad << 3);
    bf16x8 pf = *(const bf16x8*)(Prow + ko);
    #pragma unroll
    for (int cb = 0; cb < 4; cb++){
      const float* bp = bbase + (((cb << 4) + n) << 12) + ko;
      float4 b0 = *(const float4*)bp;
      float4 b1 = *(const float4*)(bp + 4);
      bf16x8 bf;
      bf[0] = (short)f2bf(b0.x); bf[1] = (short)f2bf(b0.y);
      bf[2] = (short)f2bf(b0.z); bf[3] = (short)f2bf(b0.w);
      bf[4] = (short)f2bf(b1.x); bf[5] = (short)f2bf(b1.y);
      bf[6] = (short)f2bf(b1.z); bf[7] = (short)f2bf(b1.w);
      acc[cb] = __builtin_amdgcn_mfma_f32_16x16x32_bf16(bf, pf, acc[cb], 0, 0, 0);
    }
  }
  int pql = pq0 + (wv << 4) + n;
  #pragma unroll
  for (int cb = 0; cb < 4; cb++)
    #pragma unroll
    for (int r = 0; r < 4; r++){
      int c = (cb << 4) + (quad << 2) + r;
      atomicAdd(&y[(((size_t)(bt * 64 + c)) << 12) + pql], acc[cb][r]);
    }
}

extern "C" void kernel_launch(void* const* d_in, const int* in_sizes, int n_in,
                              void* d_out, int out_size, void* d_ws, size_t ws_size,
                              hipStream_t stream){
  const float* f = (const float*)d_in[0];
  const float* b = (const float*)d_in[1];
  float* out  = (float*)d_out;
  float* yout = out;
  float* wout = out + 1048576;

  const size_t RB  = RSTRIDE * 4;   // 64 MiB fp32 R per batch
  const size_t AB  = ASTRIDE * 2;   // 32 MiB bf16 attn per batch
  const size_t SCB = SSTRIDE * 2;   // 128 KiB fp16 scale per batch
  const size_t PER = RB + AB + SCB;

  int nb = 1;
  if (ws_size >= 4 * PER) nb = 4;
  else if (ws_size >= 2 * PER) nb = 2;

  k_prep2<<<4096, 256, 0, stream>>>(b, wout, yout);   // also zeroes y

  // Layout per group: R[nb] @0 | attn[nb] @nb*RB | scale[nb] @nb*(RB+AB); P overlays R.
  float*    R     = (float*)d_ws;
  ushort_t* attn  = (ushort_t*)((char*)d_ws + (size_t)nb * RB);
  __half*   scale = (__half*)((char*)d_ws + (size_t)nb * (RB + AB));
  ushort_t* P     = (ushort_t*)d_ws;
  for (int bt0 = 0; bt0 < 4; bt0 += nb){
    k_rgemm    <<<dim3(32, 32, nb), 256, 0, stream>>>(f, b, R, bt0);
    k_softmax4 <<<dim3(512, nb),    256, 0, stream>>>(R, attn, scale);
    k_pstencil5<<<dim3(512, nb),    256, 0, stream>>>(attn, scale, P);
    k_ygemm2   <<<dim3(64, 16, nb), 256, 0, stream>>>(b, P, yout, bt0);
  }
}